// Round 6
// baseline (1089.696 us; speedup 1.0000x reference)
//
#include <hip/hip_runtime.h>
#include <hip/hip_bf16.h>

static constexpr int HN = 32;     // Hemb == Hgcn == 32
static constexpr int NIN = 128;

__device__ __forceinline__ float bf2f(unsigned short u) {
    union { unsigned int i; float f; } v;
    v.i = ((unsigned int)u) << 16;
    return v.f;
}
__device__ __forceinline__ float ldf(const void* p, size_t i, int isbf) {
    return isbf ? bf2f(((const unsigned short*)p)[i]) : ((const float*)p)[i];
}

// K0: bf16-vs-fp32 input sniff (validated: inputs are fp32; kept as insurance).
__global__ void detect_kernel(const unsigned int* __restrict__ xw,
                              int* __restrict__ flag)
{
    int lane = threadIdx.x;          // 64 threads
    int hits = 0;
    #pragma unroll
    for (int k = 0; k < 2; ++k) {
        unsigned int w = xw[lane + 64 * k];
        float a = bf2f((unsigned short)(w & 0xFFFFu));
        float aa = fabsf(a);
        if (a == 0.0f || (aa >= 0.000244140625f && aa <= 32.0f)) hits++;
    }
    #pragma unroll
    for (int m = 32; m; m >>= 1) hits += __shfl_xor(hits, m, 64);
    if (lane == 0) flag[0] = (hits >= 64) ? 1 : 0;
}

// K1: h = relu(x @ Wemb + bemb) -> fp32; hw = h @ Wgcn -> fp32.
__global__ __launch_bounds__(256) void embed_kernel(
    const void* __restrict__ x,
    const void* __restrict__ Wemb,
    const void* __restrict__ bemb,
    const void* __restrict__ Wgcn,
    const int* __restrict__ flagp,
    float* __restrict__ h, float* __restrict__ hw, int N)
{
    __shared__ float We[NIN * HN];
    __shared__ float Wg[HN * HN];
    __shared__ float be[HN];
    __shared__ float xs[32][NIN];
    __shared__ float hs[32][HN + 1];
    const int tid = threadIdx.x;
    const int isbf = flagp[0];

    for (int i = tid; i < NIN * HN; i += 256) We[i] = ldf(Wemb, i, isbf);
    for (int i = tid; i < HN * HN; i += 256) Wg[i] = ldf(Wgcn, i, isbf);
    if (tid < HN) be[tid] = ldf(bemb, tid, isbf);

    const int n0 = blockIdx.x * 32;
    if (isbf) {
        const ushort4* x4 = (const ushort4*)((const unsigned short*)x + (size_t)n0 * NIN);
        for (int i = tid; i < 32 * (NIN / 4); i += 256) {
            ushort4 u = x4[i];
            int base = i * 4, n = base >> 7, k = base & (NIN - 1);
            xs[n][k] = bf2f(u.x); xs[n][k + 1] = bf2f(u.y);
            xs[n][k + 2] = bf2f(u.z); xs[n][k + 3] = bf2f(u.w);
        }
    } else {
        const float4* x4 = (const float4*)((const float*)x + (size_t)n0 * NIN);
        for (int i = tid; i < 32 * (NIN / 4); i += 256) {
            float4 u = x4[i];
            int base = i * 4, n = base >> 7, k = base & (NIN - 1);
            xs[n][k] = u.x; xs[n][k + 1] = u.y;
            xs[n][k + 2] = u.z; xs[n][k + 3] = u.w;
        }
    }
    __syncthreads();

    const int f = tid & 31, ns = tid >> 5;   // ns in 0..7
    float a0 = be[f], a1 = be[f], a2 = be[f], a3 = be[f];
    #pragma unroll 8
    for (int k = 0; k < NIN; ++k) {
        float w = We[k * HN + f];
        a0 += xs[ns +  0][k] * w;
        a1 += xs[ns +  8][k] * w;
        a2 += xs[ns + 16][k] * w;
        a3 += xs[ns + 24][k] * w;
    }
    a0 = fmaxf(a0, 0.f); a1 = fmaxf(a1, 0.f);
    a2 = fmaxf(a2, 0.f); a3 = fmaxf(a3, 0.f);
    hs[ns][f] = a0; hs[ns + 8][f] = a1; hs[ns + 16][f] = a2; hs[ns + 24][f] = a3;
    if (n0 + ns      < N) h[(size_t)(n0 + ns     ) * HN + f] = a0;
    if (n0 + ns +  8 < N) h[(size_t)(n0 + ns +  8) * HN + f] = a1;
    if (n0 + ns + 16 < N) h[(size_t)(n0 + ns + 16) * HN + f] = a2;
    if (n0 + ns + 24 < N) h[(size_t)(n0 + ns + 24) * HN + f] = a3;
    __syncthreads();

    float g0 = 0.f, g1 = 0.f, g2 = 0.f, g3 = 0.f;
    #pragma unroll
    for (int k = 0; k < HN; ++k) {
        float w = Wg[k * HN + f];
        g0 += hs[ns][k] * w;      g1 += hs[ns + 8][k] * w;
        g2 += hs[ns + 16][k] * w; g3 += hs[ns + 24][k] * w;
    }
    if (n0 + ns      < N) hw[(size_t)(n0 + ns     ) * HN + f] = g0;
    if (n0 + ns +  8 < N) hw[(size_t)(n0 + ns +  8) * HN + f] = g1;
    if (n0 + ns + 16 < N) hw[(size_t)(n0 + ns + 16) * HN + f] = g2;
    if (n0 + ns + 24 < N) hw[(size_t)(n0 + ns + 24) * HN + f] = g3;
}

// K2: count[c] = #edges with col==c (int atomics only)
__global__ __launch_bounds__(256) void count_kernel(
    const int* __restrict__ col, int* __restrict__ count, int E)
{
    int e = blockIdx.x * 256 + threadIdx.x;
    if (e < E) atomicAdd(&count[col[e]], 1);
}

// K3a: per-2048-chunk sums
__global__ __launch_bounds__(256) void scan1_kernel(
    const int* __restrict__ count, int* __restrict__ bsum, int N)
{
    __shared__ int s[256];
    const int t = threadIdx.x, b = blockIdx.x;
    int base = b * 2048 + t * 8, sum = 0;
    #pragma unroll
    for (int k = 0; k < 8; ++k) { int i = base + k; if (i < N) sum += count[i]; }
    s[t] = sum; __syncthreads();
    for (int o = 128; o; o >>= 1) { if (t < o) s[t] += s[t + o]; __syncthreads(); }
    if (t == 0) bsum[b] = s[0];
}

// K3b: serial exclusive scan of chunk sums (nsb ~ 49); rowptr[N] = E
__global__ void scan2_kernel(int* __restrict__ bsum, int nsb,
                             int* __restrict__ rowptr, int N, int E)
{
    if (threadIdx.x == 0 && blockIdx.x == 0) {
        int acc = 0;
        for (int i = 0; i < nsb; ++i) { int v = bsum[i]; bsum[i] = acc; acc += v; }
        rowptr[N] = E;
    }
}

// K3c: rowptr = exclusive prefix of count; cursor (in-place over count) = rowptr
__global__ __launch_bounds__(256) void scan3_kernel(
    int* __restrict__ countcur, const int* __restrict__ bsum,
    int* __restrict__ rowptr, int N)
{
    __shared__ int s[256];
    const int t = threadIdx.x, b = blockIdx.x;
    int base = b * 2048 + t * 8;
    int c[8]; int sum = 0;
    #pragma unroll
    for (int k = 0; k < 8; ++k) {
        int i = base + k;
        c[k] = (i < N) ? countcur[i] : 0;
        sum += c[k];
    }
    s[t] = sum; __syncthreads();
    // Hillis-Steele inclusive scan (read-all then write-all per step)
    for (int o = 1; o < 256; o <<= 1) {
        int v = (t >= o) ? s[t - o] : 0;
        __syncthreads();
        s[t] += v;
        __syncthreads();
    }
    int acc = bsum[b] + ((t == 0) ? 0 : s[t - 1]);
    #pragma unroll
    for (int k = 0; k < 8; ++k) {
        int i = base + k;
        if (i < N) { rowptr[i] = acc; countcur[i] = acc; acc += c[k]; }
    }
}

// K4: scatter edge sources into CSR buckets (cursor = countcur)
__global__ __launch_bounds__(256) void scatter_kernel(
    const int* __restrict__ row, const int* __restrict__ col,
    int* __restrict__ cursor, int* __restrict__ csr_src, int E)
{
    int e = blockIdx.x * 256 + threadIdx.x;
    if (e >= E) return;
    int pos = atomicAdd(&cursor[col[e]], 1);
    csr_src[pos] = row[e];
}

// K5 (passA): per-node dot loop -> block max (identical dot tree as passB)
__global__ __launch_bounds__(256) void passA_kernel(
    const float* __restrict__ h,
    const int* __restrict__ csr_src, const int* __restrict__ rowptr,
    float* __restrict__ bmax, int N)
{
    const int lane = threadIdx.x & 31;
    const int v = blockIdx.x * 8 + (threadIdx.x >> 5);
    float lmax = -INFINITY;
    if (v < N) {
        float hv = h[(size_t)v * HN + lane];
        int s = rowptr[v], e2 = rowptr[v + 1];
        for (int i = s; i < e2; ++i) {
            int r = csr_src[i];
            float p = hv * h[(size_t)r * HN + lane];
            #pragma unroll
            for (int m = 16; m; m >>= 1) p += __shfl_xor(p, m, 32);
            lmax = fmaxf(lmax, p);
        }
    }
    #pragma unroll
    for (int m = 32; m; m >>= 1) lmax = fmaxf(lmax, __shfl_xor(lmax, m, 64));
    __shared__ float sm[4];
    if ((threadIdx.x & 63) == 0) sm[threadIdx.x >> 6] = lmax;
    __syncthreads();
    if (threadIdx.x == 0)
        bmax[blockIdx.x] = fmaxf(fmaxf(sm[0], sm[1]), fmaxf(sm[2], sm[3]));
}

// K6: global max over passA block maxes
__global__ __launch_bounds__(256) void amax_kernel(
    const float* __restrict__ bmax, float* __restrict__ amax, int nb)
{
    float m = -INFINITY;
    for (int i = threadIdx.x; i < nb; i += 256) m = fmaxf(m, bmax[i]);
    #pragma unroll
    for (int s = 32; s; s >>= 1) m = fmaxf(m, __shfl_xor(m, s, 64));
    __shared__ float sm[4];
    if ((threadIdx.x & 63) == 0) sm[threadIdx.x >> 6] = m;
    __syncthreads();
    if (threadIdx.x == 0) amax[0] = fmaxf(fmaxf(sm[0], sm[1]), fmaxf(sm[2], sm[3]));
}

// K7 (passB): fully fused per-node pass, zero atomics.
// Uses exact edge-list symmetry: deno/znum per row == per col (dot symmetric).
__global__ __launch_bounds__(256) void passB_kernel(
    const float* __restrict__ h, const float* __restrict__ hw,
    const int* __restrict__ csr_src, const int* __restrict__ rowptr,
    const void* __restrict__ t,
    const void* __restrict__ bgcn,
    const void* __restrict__ W1, const void* __restrict__ b1,
    const void* __restrict__ W2, const void* __restrict__ b2,
    const int* __restrict__ flagp, const float* __restrict__ amax,
    float* __restrict__ out0, float* __restrict__ outr,
    float* __restrict__ outz, int N)
{
    __shared__ float W1s[34 * HN];
    __shared__ float b1s[HN], W2s[HN], bgs[HN];
    __shared__ float b2s;
    const int tid = threadIdx.x;
    const int isbf = flagp[0];
    for (int i = tid; i < 34 * HN; i += 256) W1s[i] = ldf(W1, i, isbf);
    if (tid < HN) {
        b1s[tid] = ldf(b1, tid, isbf);
        W2s[tid] = ldf(W2, tid, isbf);
        bgs[tid] = ldf(bgcn, tid, isbf);
    }
    if (tid == 0) b2s = ldf(b2, 0, isbf);
    __syncthreads();

    const int lane = tid & 31;
    const int v = blockIdx.x * 8 + (tid >> 5);
    if (v >= N) return;

    const float am = amax[0];
    float hv = h[(size_t)v * HN + lane];
    float wv = hw[(size_t)v * HN + lane];
    int s = rowptr[v], e2 = rowptr[v + 1];

    float aggl = 0.f, deno = 0.f, znum = 0.f;
    for (int i = s; i < e2; ++i) {
        int r = csr_src[i];
        float p = hv * h[(size_t)r * HN + lane];
        #pragma unroll
        for (int m = 16; m; m >>= 1) p += __shfl_xor(p, m, 32);
        float a = expf(p - am);
        deno += a;
        znum += a * ldf(t, r, isbf);
        int degr = rowptr[r + 1] - rowptr[r];
        float disr = rsqrtf((float)degr + 1.0f);
        aggl += disr * hw[(size_t)r * HN + lane];
    }

    float dv = rsqrtf((float)(e2 - s) + 1.0f);
    float gcn = dv * aggl + dv * dv * wv + bgs[lane];
    float rep = hv + fmaxf(gcn, 0.f);
    float z = znum / (deno + 1e-8f);
    float tv = ldf(t, v, isbf);

    float acc = b1s[lane] + tv * W1s[32 * HN + lane] + z * W1s[33 * HN + lane];
    #pragma unroll
    for (int k = 0; k < HN; ++k)
        acc += __shfl(rep, k, 32) * W1s[k * HN + lane];
    float f1 = fmaxf(acc, 0.f);
    float o = f1 * W2s[lane];
    #pragma unroll
    for (int m = 16; m; m >>= 1) o += __shfl_xor(o, m, 32);

    outr[(size_t)v * HN + lane] = rep;
    if (lane == 0) {
        out0[v] = o + b2s;
        outz[v] = z;
    }
}

extern "C" void kernel_launch(void* const* d_in, const int* in_sizes, int n_in,
                              void* d_out, int out_size, void* d_ws, size_t ws_size,
                              hipStream_t stream)
{
    const int N = out_size / 34;   // out[N] + rep[N*32] + z[N]
    const int E = in_sizes[2];

    const void* x    = d_in[0];
    const void* t    = d_in[1];
    const int* row   = (const int*)d_in[2];
    const int* col   = (const int*)d_in[3];
    const void* Wemb = d_in[4];
    const void* bemb = d_in[5];
    const void* Wgcn = d_in[6];
    const void* bgcn = d_in[7];
    const void* W1   = d_in[8];
    const void* b1   = d_in[9];
    const void* W2   = d_in[10];
    const void* b2   = d_in[11];

    const int NBA = (N + 7) / 8;          // passA/passB grid
    const int nsb = (N + 2047) / 2048;    // scan chunks

    // ws layout (~39.3 MB): h | hw | csr_src | rowptr | count/cursor | bmax
    //                       | bsum | amax | flag
    char* wsb = (char*)d_ws;
    size_t off = 0;
    float* h       = (float*)(wsb + off); off += (size_t)N * HN * 4;
    float* hw      = (float*)(wsb + off); off += (size_t)N * HN * 4;
    int*   csr_src = (int*)(wsb + off);   off += (size_t)E * 4;
    int*   rowptr  = (int*)(wsb + off);   off += (size_t)(N + 1) * 4;
    int*   count   = (int*)(wsb + off);   off += (size_t)N * 4;   // becomes cursor
    float* bmax    = (float*)(wsb + off); off += (size_t)NBA * 4;
    int*   bsum    = (int*)(wsb + off);   off += (size_t)nsb * 4;
    float* amax    = (float*)(wsb + off); off += 4;
    int*   flag    = (int*)(wsb + off);   off += 4;

    hipMemsetAsync(count, 0, (size_t)N * 4, stream);

    detect_kernel<<<1, 64, 0, stream>>>((const unsigned int*)x, flag);
    embed_kernel<<<(N + 31) / 32, 256, 0, stream>>>(x, Wemb, bemb, Wgcn, flag,
                                                    h, hw, N);
    count_kernel<<<(E + 255) / 256, 256, 0, stream>>>(col, count, E);
    scan1_kernel<<<nsb, 256, 0, stream>>>(count, bsum, N);
    scan2_kernel<<<1, 64, 0, stream>>>(bsum, nsb, rowptr, N, E);
    scan3_kernel<<<nsb, 256, 0, stream>>>(count, bsum, rowptr, N);
    scatter_kernel<<<(E + 255) / 256, 256, 0, stream>>>(row, col, count,
                                                        csr_src, E);
    passA_kernel<<<NBA, 256, 0, stream>>>(h, csr_src, rowptr, bmax, N);
    amax_kernel<<<1, 256, 0, stream>>>(bmax, amax, NBA);

    float* outp = (float*)d_out;
    passB_kernel<<<NBA, 256, 0, stream>>>(
        h, hw, csr_src, rowptr, t, bgcn, W1, b1, W2, b2, flag, amax,
        outp, outp + N, outp + (size_t)N * 33, N);
}

// Round 7
// 728.967 us; speedup vs baseline: 1.4949x; 1.4949x over previous
//
#include <hip/hip_runtime.h>
#include <hip/hip_bf16.h>

static constexpr int HN = 32;     // Hemb == Hgcn == 32
static constexpr int NIN = 128;

__device__ __forceinline__ float bf2f(unsigned short u) {
    union { unsigned int i; float f; } v;
    v.i = ((unsigned int)u) << 16;
    return v.f;
}
__device__ __forceinline__ float ldf(const void* p, size_t i, int isbf) {
    return isbf ? bf2f(((const unsigned short*)p)[i]) : ((const float*)p)[i];
}

// K0: bf16-vs-fp32 input sniff (validated fp32; kept as insurance).
__global__ void detect_kernel(const unsigned int* __restrict__ xw,
                              int* __restrict__ flag)
{
    int lane = threadIdx.x;          // 64 threads
    int hits = 0;
    #pragma unroll
    for (int k = 0; k < 2; ++k) {
        unsigned int w = xw[lane + 64 * k];
        float a = bf2f((unsigned short)(w & 0xFFFFu));
        float aa = fabsf(a);
        if (a == 0.0f || (aa >= 0.000244140625f && aa <= 32.0f)) hits++;
    }
    #pragma unroll
    for (int m = 32; m; m >>= 1) hits += __shfl_xor(hits, m, 64);
    if (lane == 0) flag[0] = (hits >= 64) ? 1 : 0;
}

// K1: h = relu(x @ Wemb + bemb) -> fp32; hw = h @ Wgcn -> fp32.
__global__ __launch_bounds__(256) void embed_kernel(
    const void* __restrict__ x,
    const void* __restrict__ Wemb,
    const void* __restrict__ bemb,
    const void* __restrict__ Wgcn,
    const int* __restrict__ flagp,
    float* __restrict__ h, float* __restrict__ hw, int N)
{
    __shared__ float We[NIN * HN];
    __shared__ float Wg[HN * HN];
    __shared__ float be[HN];
    __shared__ float xs[32][NIN];
    __shared__ float hs[32][HN + 1];
    const int tid = threadIdx.x;
    const int isbf = flagp[0];

    for (int i = tid; i < NIN * HN; i += 256) We[i] = ldf(Wemb, i, isbf);
    for (int i = tid; i < HN * HN; i += 256) Wg[i] = ldf(Wgcn, i, isbf);
    if (tid < HN) be[tid] = ldf(bemb, tid, isbf);

    const int n0 = blockIdx.x * 32;
    if (isbf) {
        const ushort4* x4 = (const ushort4*)((const unsigned short*)x + (size_t)n0 * NIN);
        for (int i = tid; i < 32 * (NIN / 4); i += 256) {
            ushort4 u = x4[i];
            int base = i * 4, n = base >> 7, k = base & (NIN - 1);
            xs[n][k] = bf2f(u.x); xs[n][k + 1] = bf2f(u.y);
            xs[n][k + 2] = bf2f(u.z); xs[n][k + 3] = bf2f(u.w);
        }
    } else {
        const float4* x4 = (const float4*)((const float*)x + (size_t)n0 * NIN);
        for (int i = tid; i < 32 * (NIN / 4); i += 256) {
            float4 u = x4[i];
            int base = i * 4, n = base >> 7, k = base & (NIN - 1);
            xs[n][k] = u.x; xs[n][k + 1] = u.y;
            xs[n][k + 2] = u.z; xs[n][k + 3] = u.w;
        }
    }
    __syncthreads();

    const int f = tid & 31, ns = tid >> 5;   // ns in 0..7
    float a0 = be[f], a1 = be[f], a2 = be[f], a3 = be[f];
    #pragma unroll 8
    for (int k = 0; k < NIN; ++k) {
        float w = We[k * HN + f];
        a0 += xs[ns +  0][k] * w;
        a1 += xs[ns +  8][k] * w;
        a2 += xs[ns + 16][k] * w;
        a3 += xs[ns + 24][k] * w;
    }
    a0 = fmaxf(a0, 0.f); a1 = fmaxf(a1, 0.f);
    a2 = fmaxf(a2, 0.f); a3 = fmaxf(a3, 0.f);
    hs[ns][f] = a0; hs[ns + 8][f] = a1; hs[ns + 16][f] = a2; hs[ns + 24][f] = a3;
    if (n0 + ns      < N) h[(size_t)(n0 + ns     ) * HN + f] = a0;
    if (n0 + ns +  8 < N) h[(size_t)(n0 + ns +  8) * HN + f] = a1;
    if (n0 + ns + 16 < N) h[(size_t)(n0 + ns + 16) * HN + f] = a2;
    if (n0 + ns + 24 < N) h[(size_t)(n0 + ns + 24) * HN + f] = a3;
    __syncthreads();

    float g0 = 0.f, g1 = 0.f, g2 = 0.f, g3 = 0.f;
    #pragma unroll
    for (int k = 0; k < HN; ++k) {
        float w = Wg[k * HN + f];
        g0 += hs[ns][k] * w;      g1 += hs[ns + 8][k] * w;
        g2 += hs[ns + 16][k] * w; g3 += hs[ns + 24][k] * w;
    }
    if (n0 + ns      < N) hw[(size_t)(n0 + ns     ) * HN + f] = g0;
    if (n0 + ns +  8 < N) hw[(size_t)(n0 + ns +  8) * HN + f] = g1;
    if (n0 + ns + 16 < N) hw[(size_t)(n0 + ns + 16) * HN + f] = g2;
    if (n0 + ns + 24 < N) hw[(size_t)(n0 + ns + 24) * HN + f] = g3;
}

// K2: count[c] = #edges with col==c (int atomics only)
__global__ __launch_bounds__(256) void count_kernel(
    const int* __restrict__ col, int* __restrict__ count, int E)
{
    int e = blockIdx.x * 256 + threadIdx.x;
    if (e < E) atomicAdd(&count[col[e]], 1);
}

// K3a: per-2048-chunk sums
__global__ __launch_bounds__(256) void scan1_kernel(
    const int* __restrict__ count, int* __restrict__ bsum, int N)
{
    __shared__ int s[256];
    const int t = threadIdx.x, b = blockIdx.x;
    int base = b * 2048 + t * 8, sum = 0;
    #pragma unroll
    for (int k = 0; k < 8; ++k) { int i = base + k; if (i < N) sum += count[i]; }
    s[t] = sum; __syncthreads();
    for (int o = 128; o; o >>= 1) { if (t < o) s[t] += s[t + o]; __syncthreads(); }
    if (t == 0) bsum[b] = s[0];
}

// K3b: serial exclusive scan of chunk sums (nsb ~ 49); rowptr[N] = E
__global__ void scan2_kernel(int* __restrict__ bsum, int nsb,
                             int* __restrict__ rowptr, int N, int E)
{
    if (threadIdx.x == 0 && blockIdx.x == 0) {
        int acc = 0;
        for (int i = 0; i < nsb; ++i) { int v = bsum[i]; bsum[i] = acc; acc += v; }
        rowptr[N] = E;
    }
}

// K3c: rowptr = exclusive prefix of count; cursor (in-place over count) = rowptr
__global__ __launch_bounds__(256) void scan3_kernel(
    int* __restrict__ countcur, const int* __restrict__ bsum,
    int* __restrict__ rowptr, int N)
{
    __shared__ int s[256];
    const int t = threadIdx.x, b = blockIdx.x;
    int base = b * 2048 + t * 8;
    int c[8]; int sum = 0;
    #pragma unroll
    for (int k = 0; k < 8; ++k) {
        int i = base + k;
        c[k] = (i < N) ? countcur[i] : 0;
        sum += c[k];
    }
    s[t] = sum; __syncthreads();
    for (int o = 1; o < 256; o <<= 1) {
        int v = (t >= o) ? s[t - o] : 0;
        __syncthreads();
        s[t] += v;
        __syncthreads();
    }
    int acc = bsum[b] + ((t == 0) ? 0 : s[t - 1]);
    #pragma unroll
    for (int k = 0; k < 8; ++k) {
        int i = base + k;
        if (i < N) { rowptr[i] = acc; countcur[i] = acc; acc += c[k]; }
    }
}

// K4: scatter edge sources into CSR buckets (cursor = countcur)
__global__ __launch_bounds__(256) void scatter_kernel(
    const int* __restrict__ row, const int* __restrict__ col,
    int* __restrict__ cursor, int* __restrict__ csr_src, int E)
{
    int e = blockIdx.x * 256 + threadIdx.x;
    if (e >= E) return;
    int pos = atomicAdd(&cursor[col[e]], 1);
    csr_src[pos] = row[e];
}

// K5 (passB): single fused gather pass, online softmax, zero fp32 atomics.
// 32 lanes per node; 4 subgroups of 8 lanes each walk every 4th in-edge with
// float4 loads. Writes rep -> outr, zhat=num/den -> outz, ml -> out0,
// den -> denout (reused cursor array).
__global__ __launch_bounds__(256) void passB_kernel(
    const float* __restrict__ h, const float* __restrict__ hw,
    const int* __restrict__ csr_src, const int* __restrict__ rowptr,
    const void* __restrict__ t, const void* __restrict__ bgcn,
    const int* __restrict__ flagp,
    float* __restrict__ outr, float* __restrict__ outz,
    float* __restrict__ out0_ml, float* __restrict__ denout, int N)
{
    const int tid = threadIdx.x;
    const int lane = tid & 31;
    const int sub = lane >> 3;       // 0..3
    const int j = lane & 7;          // float4 slot
    const int v = blockIdx.x * 8 + (tid >> 5);
    if (v >= N) return;
    const int isbf = flagp[0];

    const float4* h4 = (const float4*)h;
    const float4* hw4 = (const float4*)hw;
    float4 hv = h4[(size_t)v * 8 + j];
    float4 wv = hw4[(size_t)v * 8 + j];
    const int s = rowptr[v], e2 = rowptr[v + 1];

    float m = -1e30f, den = 0.f, num = 0.f;
    float ax = 0.f, ay = 0.f, az = 0.f, aw = 0.f;
    for (int i = s + sub; i < e2; i += 4) {
        int r = csr_src[i];
        float4 hr = h4[(size_t)r * 8 + j];
        float4 wr = hw4[(size_t)r * 8 + j];
        int r0 = rowptr[r], r1 = rowptr[r + 1];
        float tr = ldf(t, r, isbf);
        float p = hv.x * hr.x + hv.y * hr.y + hv.z * hr.z + hv.w * hr.w;
        p += __shfl_xor(p, 1, 32);
        p += __shfl_xor(p, 2, 32);
        p += __shfl_xor(p, 4, 32);
        float mn = fmaxf(m, p);
        float corr = __expf(m - mn);
        float a = __expf(p - mn);
        den = den * corr + a;
        num = num * corr + a * tr;
        m = mn;
        float disr = rsqrtf((float)(r1 - r0) + 1.0f);
        ax += disr * wr.x; ay += disr * wr.y;
        az += disr * wr.z; aw += disr * wr.w;
    }
    // merge 4 subgroups (butterfly: xor 8, xor 16 within width 32)
    #pragma unroll
    for (int o = 8; o <= 16; o <<= 1) {
        float mo = __shfl_xor(m, o, 32);
        float dno = __shfl_xor(den, o, 32);
        float nmo = __shfl_xor(num, o, 32);
        float mn = fmaxf(m, mo);
        float ca = __expf(m - mn), cb = __expf(mo - mn);
        den = den * ca + dno * cb;
        num = num * ca + nmo * cb;
        m = mn;
        ax += __shfl_xor(ax, o, 32);
        ay += __shfl_xor(ay, o, 32);
        az += __shfl_xor(az, o, 32);
        aw += __shfl_xor(aw, o, 32);
    }

    float dv = rsqrtf((float)(e2 - s) + 1.0f);
    float4 rep;
    rep.x = hv.x + fmaxf(dv * ax + dv * dv * wv.x + ldf(bgcn, 4 * j + 0, isbf), 0.f);
    rep.y = hv.y + fmaxf(dv * ay + dv * dv * wv.y + ldf(bgcn, 4 * j + 1, isbf), 0.f);
    rep.z = hv.z + fmaxf(dv * az + dv * dv * wv.z + ldf(bgcn, 4 * j + 2, isbf), 0.f);
    rep.w = hv.w + fmaxf(dv * aw + dv * dv * wv.w + ldf(bgcn, 4 * j + 3, isbf), 0.f);
    if (sub == 0)
        ((float4*)outr)[(size_t)v * 8 + j] = rep;
    if (lane == 0) {
        outz[v]    = num / fmaxf(den, 1e-37f);   // zhat
        out0_ml[v] = m;                          // local max (am reduction later)
        denout[v]  = den;
    }
}

// K6a/K6b: global max over per-node local maxes (stored in out0)
__global__ __launch_bounds__(256) void amax1_kernel(
    const float* __restrict__ ml, float* __restrict__ bmax2, int N)
{
    float m = -INFINITY;
    for (int i = blockIdx.x * 256 + threadIdx.x; i < N; i += 256 * 256)
        m = fmaxf(m, ml[i]);
    #pragma unroll
    for (int s = 32; s; s >>= 1) m = fmaxf(m, __shfl_xor(m, s, 64));
    __shared__ float sm[4];
    if ((threadIdx.x & 63) == 0) sm[threadIdx.x >> 6] = m;
    __syncthreads();
    if (threadIdx.x == 0)
        bmax2[blockIdx.x] = fmaxf(fmaxf(sm[0], sm[1]), fmaxf(sm[2], sm[3]));
}
__global__ __launch_bounds__(256) void amax2_kernel(
    const float* __restrict__ bmax2, float* __restrict__ amax)
{
    float m = bmax2[threadIdx.x];
    #pragma unroll
    for (int s = 32; s; s >>= 1) m = fmaxf(m, __shfl_xor(m, s, 64));
    __shared__ float sm[4];
    if ((threadIdx.x & 63) == 0) sm[threadIdx.x >> 6] = m;
    __syncthreads();
    if (threadIdx.x == 0) amax[0] = fmaxf(fmaxf(sm[0], sm[1]), fmaxf(sm[2], sm[3]));
}

// K7: exact epsilon correction + FF head. Reads ml from out0 / zhat from outz
// (owner-only read-then-write), rep from outr.
__global__ __launch_bounds__(256) void final_kernel(
    const float* __restrict__ rep_in,
    const void* __restrict__ t, const int* __restrict__ flagp,
    const float* __restrict__ amax, const float* __restrict__ denarr,
    const void* __restrict__ W1, const void* __restrict__ b1,
    const void* __restrict__ W2, const void* __restrict__ b2,
    float* __restrict__ out0, float* __restrict__ outz, int N)
{
    __shared__ float W1s[34 * HN];
    __shared__ float b1s[HN], W2s[HN];
    __shared__ float b2s;
    const int tid = threadIdx.x;
    const int isbf = flagp[0];
    for (int i = tid; i < 34 * HN; i += 256) W1s[i] = ldf(W1, i, isbf);
    if (tid < HN) {
        b1s[tid] = ldf(b1, tid, isbf);
        W2s[tid] = ldf(W2, tid, isbf);
    }
    if (tid == 0) b2s = ldf(b2, 0, isbf);
    __syncthreads();

    const int lane = tid & 31;
    const int v = blockIdx.x * 8 + (tid >> 5);
    if (v >= N) return;

    float rep = rep_in[(size_t)v * HN + lane];
    float ml  = out0[v];
    float den = denarr[v];
    float zh  = outz[v];
    float am  = amax[0];
    // exact: z = num/(den + 1e-8*exp(am-ml)) = zh / (1 + (1e-8/den)*exp(am-ml))
    float term = (1e-8f / den) * expf(am - ml);
    float z = zh / (1.0f + term);
    float tv = ldf(t, v, isbf);

    float acc = b1s[lane] + tv * W1s[32 * HN + lane] + z * W1s[33 * HN + lane];
    #pragma unroll
    for (int k = 0; k < HN; ++k)
        acc += __shfl(rep, k, 32) * W1s[k * HN + lane];
    float f1 = fmaxf(acc, 0.f);
    float o = f1 * W2s[lane];
    #pragma unroll
    for (int m = 16; m; m >>= 1) o += __shfl_xor(o, m, 32);

    if (lane == 0) {
        out0[v] = o + b2s;
        outz[v] = z;
    }
}

extern "C" void kernel_launch(void* const* d_in, const int* in_sizes, int n_in,
                              void* d_out, int out_size, void* d_ws, size_t ws_size,
                              hipStream_t stream)
{
    const int N = out_size / 34;   // out[N] + rep[N*32] + z[N]
    const int E = in_sizes[2];

    const void* x    = d_in[0];
    const void* t    = d_in[1];
    const int* row   = (const int*)d_in[2];
    const int* col   = (const int*)d_in[3];
    const void* Wemb = d_in[4];
    const void* bemb = d_in[5];
    const void* Wgcn = d_in[6];
    const void* bgcn = d_in[7];
    const void* W1   = d_in[8];
    const void* b1   = d_in[9];
    const void* W2   = d_in[10];
    const void* b2   = d_in[11];

    const int nsb = (N + 2047) / 2048;    // scan chunks

    // ws layout (39.2 MB total, under the 39.25 MB proven in round 6):
    //   h | hw | csr_src | rowptr | count(cursor->den) | bmax2 | bsum | amax | flag
    char* wsb = (char*)d_ws;
    size_t off = 0;
    float* h       = (float*)(wsb + off); off += (size_t)N * HN * 4;
    float* hw      = (float*)(wsb + off); off += (size_t)N * HN * 4;
    int*   csr_src = (int*)(wsb + off);   off += (size_t)E * 4;
    int*   rowptr  = (int*)(wsb + off);   off += (size_t)(N + 1) * 4;
    int*   count   = (int*)(wsb + off);   off += (size_t)N * 4;   // cursor, then den
    float* bmax2   = (float*)(wsb + off); off += 256 * 4;
    int*   bsum    = (int*)(wsb + off);   off += (size_t)nsb * 4;
    float* amax    = (float*)(wsb + off); off += 4;
    int*   flag    = (int*)(wsb + off);   off += 4;

    hipMemsetAsync(count, 0, (size_t)N * 4, stream);

    detect_kernel<<<1, 64, 0, stream>>>((const unsigned int*)x, flag);
    embed_kernel<<<(N + 31) / 32, 256, 0, stream>>>(x, Wemb, bemb, Wgcn, flag,
                                                    h, hw, N);
    count_kernel<<<(E + 255) / 256, 256, 0, stream>>>(col, count, E);
    scan1_kernel<<<nsb, 256, 0, stream>>>(count, bsum, N);
    scan2_kernel<<<1, 64, 0, stream>>>(bsum, nsb, rowptr, N, E);
    scan3_kernel<<<nsb, 256, 0, stream>>>(count, bsum, rowptr, N);
    scatter_kernel<<<(E + 255) / 256, 256, 0, stream>>>(row, col, count,
                                                        csr_src, E);

    float* outp = (float*)d_out;
    float* out0 = outp;
    float* outr = outp + N;
    float* outz = outp + (size_t)N * 33;
    float* den  = (float*)count;   // cursor dead after scatter

    passB_kernel<<<(N + 7) / 8, 256, 0, stream>>>(
        h, hw, csr_src, rowptr, t, bgcn, flag, outr, outz, out0, den, N);
    amax1_kernel<<<256, 256, 0, stream>>>(out0, bmax2, N);
    amax2_kernel<<<1, 256, 0, stream>>>(bmax2, amax);
    final_kernel<<<(N + 7) / 8, 256, 0, stream>>>(
        outr, t, flag, amax, den, W1, b1, W2, b2, out0, outz, N);
}

// Round 8
// 402.323 us; speedup vs baseline: 2.7085x; 1.8119x over previous
//
#include <hip/hip_runtime.h>
#include <hip/hip_bf16.h>

static constexpr int HN = 32;     // Hemb == Hgcn == 32
static constexpr int NIN = 128;
static constexpr int CH1 = 8192;  // edges per phase-1 block
static constexpr int CAP2 = 16384; // LDS stage capacity (ints) in phase 2b

__device__ __forceinline__ float bf2f(unsigned short u) {
    union { unsigned int i; float f; } v;
    v.i = ((unsigned int)u) << 16;
    return v.f;
}
__device__ __forceinline__ float ldf(const void* p, size_t i, int isbf) {
    return isbf ? bf2f(((const unsigned short*)p)[i]) : ((const float*)p)[i];
}

// K0: bf16-vs-fp32 input sniff (validated fp32; kept as insurance).
__global__ void detect_kernel(const unsigned int* __restrict__ xw,
                              int* __restrict__ flag)
{
    int lane = threadIdx.x;          // 64 threads
    int hits = 0;
    #pragma unroll
    for (int k = 0; k < 2; ++k) {
        unsigned int w = xw[lane + 64 * k];
        float a = bf2f((unsigned short)(w & 0xFFFFu));
        float aa = fabsf(a);
        if (a == 0.0f || (aa >= 0.000244140625f && aa <= 32.0f)) hits++;
    }
    #pragma unroll
    for (int m = 32; m; m >>= 1) hits += __shfl_xor(hits, m, 64);
    if (lane == 0) flag[0] = (hits >= 64) ? 1 : 0;
}

// K1: h = relu(x @ Wemb + bemb) -> fp32 (hw computed later as hws).
__global__ __launch_bounds__(256) void embed1_kernel(
    const void* __restrict__ x,
    const void* __restrict__ Wemb,
    const void* __restrict__ bemb,
    const int* __restrict__ flagp,
    float* __restrict__ h, int N)
{
    __shared__ float We[NIN * HN];
    __shared__ float be[HN];
    __shared__ float xs[32][NIN];
    const int tid = threadIdx.x;
    const int isbf = flagp[0];

    for (int i = tid; i < NIN * HN; i += 256) We[i] = ldf(Wemb, i, isbf);
    if (tid < HN) be[tid] = ldf(bemb, tid, isbf);

    const int n0 = blockIdx.x * 32;
    if (isbf) {
        const ushort4* x4 = (const ushort4*)((const unsigned short*)x + (size_t)n0 * NIN);
        for (int i = tid; i < 32 * (NIN / 4); i += 256) {
            ushort4 u = x4[i];
            int base = i * 4, n = base >> 7, k = base & (NIN - 1);
            xs[n][k] = bf2f(u.x); xs[n][k + 1] = bf2f(u.y);
            xs[n][k + 2] = bf2f(u.z); xs[n][k + 3] = bf2f(u.w);
        }
    } else {
        const float4* x4 = (const float4*)((const float*)x + (size_t)n0 * NIN);
        for (int i = tid; i < 32 * (NIN / 4); i += 256) {
            float4 u = x4[i];
            int base = i * 4, n = base >> 7, k = base & (NIN - 1);
            xs[n][k] = u.x; xs[n][k + 1] = u.y;
            xs[n][k + 2] = u.z; xs[n][k + 3] = u.w;
        }
    }
    __syncthreads();

    const int f = tid & 31, ns = tid >> 5;
    float a0 = be[f], a1 = be[f], a2 = be[f], a3 = be[f];
    #pragma unroll 8
    for (int k = 0; k < NIN; ++k) {
        float w = We[k * HN + f];
        a0 += xs[ns +  0][k] * w;
        a1 += xs[ns +  8][k] * w;
        a2 += xs[ns + 16][k] * w;
        a3 += xs[ns + 24][k] * w;
    }
    if (n0 + ns      < N) h[(size_t)(n0 + ns     ) * HN + f] = fmaxf(a0, 0.f);
    if (n0 + ns +  8 < N) h[(size_t)(n0 + ns +  8) * HN + f] = fmaxf(a1, 0.f);
    if (n0 + ns + 16 < N) h[(size_t)(n0 + ns + 16) * HN + f] = fmaxf(a2, 0.f);
    if (n0 + ns + 24 < N) h[(size_t)(n0 + ns + 24) * HN + f] = fmaxf(a3, 0.f);
}

// K2: coarse bucket histogram (bucket = col>>8), LDS-aggregated.
__global__ __launch_bounds__(512) void bhist_kernel(
    const int* __restrict__ col, int* __restrict__ bucket_cnt, int E, int B)
{
    __shared__ int hist[512];
    const int t = threadIdx.x;
    const int e0 = blockIdx.x * CH1;
    for (int i = t; i < B; i += 512) hist[i] = 0;
    __syncthreads();
    #pragma unroll
    for (int k = 0; k < CH1 / 512; ++k) {
        int e = e0 + k * 512 + t;
        if (e < E) atomicAdd(&hist[col[e] >> 8], 1);
    }
    __syncthreads();
    for (int i = t; i < B; i += 512)
        if (hist[i]) atomicAdd(&bucket_cnt[i], hist[i]);
}

// K3: exclusive scan of bucket counts (B <= 512); init cursors.
__global__ __launch_bounds__(512) void bscan_kernel(
    const int* __restrict__ bucket_cnt, int* __restrict__ bucket_base,
    int* __restrict__ bucket_cursor, int B, int E)
{
    __shared__ int sc[512];
    __shared__ int orig[512];
    const int t = threadIdx.x;
    int v0 = (t < B) ? bucket_cnt[t] : 0;
    sc[t] = v0; orig[t] = v0;
    __syncthreads();
    for (int o = 1; o < 512; o <<= 1) {
        int v = (t >= o) ? sc[t - o] : 0;
        __syncthreads();
        sc[t] += v;
        __syncthreads();
    }
    if (t < B) {
        int ex = sc[t] - orig[t];
        bucket_base[t] = ex;
        bucket_cursor[t] = ex;
    }
    if (t == 0) bucket_base[B] = E;
}

// K4 (phase1): bucketize edges with LDS reorder -> semi-coalesced writes of
// packed words (row<<8 | col&255) grouped by bucket.
__global__ __launch_bounds__(512) void phase1_kernel(
    const int* __restrict__ row, const int* __restrict__ col,
    int* __restrict__ bucket_cursor, int* __restrict__ bucketed, int E, int B)
{
    __shared__ int hist[512];
    __shared__ int sc[512];
    __shared__ int cnt[512];
    __shared__ int gbase[512];
    __shared__ int word[CH1];
    __shared__ int dst[CH1];
    const int t = threadIdx.x;
    const int e0 = blockIdx.x * CH1;
    const int M = (E - e0 < CH1) ? (E - e0) : CH1;

    for (int i = t; i < B; i += 512) { hist[i] = 0; cnt[i] = 0; }
    __syncthreads();
    #pragma unroll
    for (int k = 0; k < CH1 / 512; ++k) {
        int e = e0 + k * 512 + t;
        if (e < E) atomicAdd(&hist[col[e] >> 8], 1);
    }
    __syncthreads();
    sc[t] = (t < B) ? hist[t] : 0;
    __syncthreads();
    for (int o = 1; o < 512; o <<= 1) {
        int v = (t >= o) ? sc[t - o] : 0;
        __syncthreads();
        sc[t] += v;
        __syncthreads();
    }
    if (t < B && hist[t])
        gbase[t] = atomicAdd(&bucket_cursor[t], hist[t]);
    __syncthreads();
    #pragma unroll
    for (int k = 0; k < CH1 / 512; ++k) {
        int e = e0 + k * 512 + t;
        if (e < E) {
            int c = col[e], r = row[e];
            int b = c >> 8;
            int lr = atomicAdd(&cnt[b], 1);
            int p = sc[b] - hist[b] + lr;     // exclusive scan + rank
            word[p] = (r << 8) | (c & 255);
            dst[p] = gbase[b] + lr;
        }
    }
    __syncthreads();
    for (int i = t; i < M; i += 512)
        bucketed[dst[i]] = word[i];
}

// K5 (phase2a): per-node degree counts from bucketed words (coalesced writes).
__global__ __launch_bounds__(256) void phase2a_kernel(
    const int* __restrict__ bucketed, const int* __restrict__ bucket_base,
    int* __restrict__ count, int N)
{
    __shared__ int cnt[256];
    const int t = threadIdx.x, b = blockIdx.x;
    cnt[t] = 0;
    __syncthreads();
    const int s0 = bucket_base[b], s1 = bucket_base[b + 1];
    for (int i = s0 + t; i < s1; i += 256)
        atomicAdd(&cnt[bucketed[i] & 255], 1);
    __syncthreads();
    int node = (b << 8) + t;
    if (node < N) count[node] = cnt[t];
}

// K6a: per-2048-chunk sums (for rowptr scan)
__global__ __launch_bounds__(256) void scan1_kernel(
    const int* __restrict__ count, int* __restrict__ bsum, int N)
{
    __shared__ int s[256];
    const int t = threadIdx.x, b = blockIdx.x;
    int base = b * 2048 + t * 8, sum = 0;
    #pragma unroll
    for (int k = 0; k < 8; ++k) { int i = base + k; if (i < N) sum += count[i]; }
    s[t] = sum; __syncthreads();
    for (int o = 128; o; o >>= 1) { if (t < o) s[t] += s[t + o]; __syncthreads(); }
    if (t == 0) bsum[b] = s[0];
}

// K6b: serial exclusive scan of chunk sums; rowptr[N] = E
__global__ void scan2_kernel(int* __restrict__ bsum, int nsb,
                             int* __restrict__ rowptr, int N, int E)
{
    if (threadIdx.x == 0 && blockIdx.x == 0) {
        int acc = 0;
        for (int i = 0; i < nsb; ++i) { int v = bsum[i]; bsum[i] = acc; acc += v; }
        rowptr[N] = E;
    }
}

// K6c: rowptr = exclusive prefix of count; cursor (in-place) = rowptr
__global__ __launch_bounds__(256) void scan3_kernel(
    int* __restrict__ countcur, const int* __restrict__ bsum,
    int* __restrict__ rowptr, int N)
{
    __shared__ int s[256];
    const int t = threadIdx.x, b = blockIdx.x;
    int base = b * 2048 + t * 8;
    int c[8]; int sum = 0;
    #pragma unroll
    for (int k = 0; k < 8; ++k) {
        int i = base + k;
        c[k] = (i < N) ? countcur[i] : 0;
        sum += c[k];
    }
    s[t] = sum; __syncthreads();
    for (int o = 1; o < 256; o <<= 1) {
        int v = (t >= o) ? s[t - o] : 0;
        __syncthreads();
        s[t] += v;
        __syncthreads();
    }
    int acc = bsum[b] + ((t == 0) ? 0 : s[t - 1]);
    #pragma unroll
    for (int k = 0; k < 8; ++k) {
        int i = base + k;
        if (i < N) { rowptr[i] = acc; countcur[i] = acc; acc += c[k]; }
    }
}

// K7 (phase2b): fine CSR placement. One block per bucket; stage segment in
// LDS, copy out fully coalesced. rowptr[node0] == bucket_base[b] exactly.
__global__ __launch_bounds__(256) void phase2b_kernel(
    const int* __restrict__ bucketed, const int* __restrict__ bucket_base,
    const int* __restrict__ rowptr, int* __restrict__ cursor,
    int* __restrict__ csr_src, int N)
{
    __shared__ int stage[CAP2];
    __shared__ int rps[257];
    __shared__ int cnt[256];
    const int t = threadIdx.x, b = blockIdx.x;
    const int s0 = bucket_base[b], s1 = bucket_base[b + 1];
    const int segsz = s1 - s0;
    const int node0 = b << 8;
    const int nodes = (N - node0 < 256) ? (N - node0) : 256;
    if (t <= nodes) rps[t] = rowptr[node0 + t];
    cnt[t] = 0;
    __syncthreads();
    if (segsz <= CAP2) {
        for (int i = s0 + t; i < s1; i += 256) {
            int w = bucketed[i];
            int lc = w & 255;
            int off = rps[lc] - s0 + atomicAdd(&cnt[lc], 1);
            stage[off] = w >> 8;
        }
        __syncthreads();
        for (int i = t; i < segsz; i += 256) csr_src[s0 + i] = stage[i];
    } else {
        for (int i = s0 + t; i < s1; i += 256) {
            int w = bucketed[i];
            int pos = atomicAdd(&cursor[node0 + (w & 255)], 1);
            csr_src[pos] = w >> 8;
        }
    }
}

// K8: hws = dis * (h @ Wgcn)   (overwrites the bucketed region)
__global__ __launch_bounds__(256) void embed2_kernel(
    const float* __restrict__ h, const void* __restrict__ Wgcn,
    const int* __restrict__ rowptr, const int* __restrict__ flagp,
    float* __restrict__ hws, int N)
{
    __shared__ float Wg[HN * HN];
    __shared__ float hs[32][HN + 1];
    const int tid = threadIdx.x;
    const int isbf = flagp[0];
    for (int i = tid; i < HN * HN; i += 256) Wg[i] = ldf(Wgcn, i, isbf);
    const int n0 = blockIdx.x * 32;
    for (int i = tid; i < 32 * HN; i += 256) {
        int n = i >> 5, f = i & 31;
        hs[n][f] = (n0 + n < N) ? h[(size_t)(n0 + n) * HN + f] : 0.f;
    }
    __syncthreads();
    const int f = tid & 31, ns = tid >> 5;
    #pragma unroll
    for (int g = 0; g < 4; ++g) {
        int n = ns + 8 * g, v = n0 + n;
        if (v < N) {
            float acc = 0.f;
            #pragma unroll
            for (int k = 0; k < HN; ++k) acc += hs[n][k] * Wg[k * HN + f];
            float dis = rsqrtf((float)(rowptr[v + 1] - rowptr[v]) + 1.0f);
            hws[(size_t)v * HN + f] = dis * acc;
        }
    }
}

// K9 (passB): fused gather pass, online softmax, zero fp32 atomics.
__global__ __launch_bounds__(256) void passB_kernel(
    const float* __restrict__ h, const float* __restrict__ hws,
    const int* __restrict__ csr_src, const int* __restrict__ rowptr,
    const void* __restrict__ t, const void* __restrict__ bgcn,
    const int* __restrict__ flagp,
    float* __restrict__ outr, float* __restrict__ outz,
    float* __restrict__ out0_ml, float* __restrict__ denout, int N)
{
    const int tid = threadIdx.x;
    const int lane = tid & 31;
    const int sub = lane >> 3;
    const int j = lane & 7;
    const int v = blockIdx.x * 8 + (tid >> 5);
    if (v >= N) return;
    const int isbf = flagp[0];

    const float4* h4 = (const float4*)h;
    const float4* w4 = (const float4*)hws;
    float4 hv = h4[(size_t)v * 8 + j];
    float4 wsv = w4[(size_t)v * 8 + j];
    const int s = rowptr[v], e2 = rowptr[v + 1];

    float m = -1e30f, den = 0.f, num = 0.f;
    float ax = 0.f, ay = 0.f, az = 0.f, aw = 0.f;
    for (int i = s + sub; i < e2; i += 4) {
        int r = csr_src[i];
        float4 hr = h4[(size_t)r * 8 + j];
        float4 wr = w4[(size_t)r * 8 + j];
        float tr = ldf(t, r, isbf);
        float p = hv.x * hr.x + hv.y * hr.y + hv.z * hr.z + hv.w * hr.w;
        p += __shfl_xor(p, 1, 32);
        p += __shfl_xor(p, 2, 32);
        p += __shfl_xor(p, 4, 32);
        float mn = fmaxf(m, p);
        float corr = __expf(m - mn);
        float a = __expf(p - mn);
        den = den * corr + a;
        num = num * corr + a * tr;
        m = mn;
        ax += wr.x; ay += wr.y; az += wr.z; aw += wr.w;
    }
    #pragma unroll
    for (int o = 8; o <= 16; o <<= 1) {
        float mo = __shfl_xor(m, o, 32);
        float dno = __shfl_xor(den, o, 32);
        float nmo = __shfl_xor(num, o, 32);
        float mn = fmaxf(m, mo);
        float ca = __expf(m - mn), cb = __expf(mo - mn);
        den = den * ca + dno * cb;
        num = num * ca + nmo * cb;
        m = mn;
        ax += __shfl_xor(ax, o, 32);
        ay += __shfl_xor(ay, o, 32);
        az += __shfl_xor(az, o, 32);
        aw += __shfl_xor(aw, o, 32);
    }

    float dv = rsqrtf((float)(e2 - s) + 1.0f);
    float4 rep;
    rep.x = hv.x + fmaxf(dv * (ax + wsv.x) + ldf(bgcn, 4 * j + 0, isbf), 0.f);
    rep.y = hv.y + fmaxf(dv * (ay + wsv.y) + ldf(bgcn, 4 * j + 1, isbf), 0.f);
    rep.z = hv.z + fmaxf(dv * (az + wsv.z) + ldf(bgcn, 4 * j + 2, isbf), 0.f);
    rep.w = hv.w + fmaxf(dv * (aw + wsv.w) + ldf(bgcn, 4 * j + 3, isbf), 0.f);
    if (sub == 0)
        ((float4*)outr)[(size_t)v * 8 + j] = rep;
    if (lane == 0) {
        outz[v]    = num / fmaxf(den, 1e-37f);
        out0_ml[v] = m;
        denout[v]  = den;
    }
}

// K10a/K10b: global max over per-node local maxes
__global__ __launch_bounds__(256) void amax1_kernel(
    const float* __restrict__ ml, float* __restrict__ bmax2, int N)
{
    float m = -INFINITY;
    for (int i = blockIdx.x * 256 + threadIdx.x; i < N; i += 256 * 256)
        m = fmaxf(m, ml[i]);
    #pragma unroll
    for (int s = 32; s; s >>= 1) m = fmaxf(m, __shfl_xor(m, s, 64));
    __shared__ float sm[4];
    if ((threadIdx.x & 63) == 0) sm[threadIdx.x >> 6] = m;
    __syncthreads();
    if (threadIdx.x == 0)
        bmax2[blockIdx.x] = fmaxf(fmaxf(sm[0], sm[1]), fmaxf(sm[2], sm[3]));
}
__global__ __launch_bounds__(256) void amax2_kernel(
    const float* __restrict__ bmax2, float* __restrict__ amax)
{
    float m = bmax2[threadIdx.x];
    #pragma unroll
    for (int s = 32; s; s >>= 1) m = fmaxf(m, __shfl_xor(m, s, 64));
    __shared__ float sm[4];
    if ((threadIdx.x & 63) == 0) sm[threadIdx.x >> 6] = m;
    __syncthreads();
    if (threadIdx.x == 0) amax[0] = fmaxf(fmaxf(sm[0], sm[1]), fmaxf(sm[2], sm[3]));
}

// K11: exact epsilon correction + FF head.
__global__ __launch_bounds__(256) void final_kernel(
    const float* __restrict__ rep_in,
    const void* __restrict__ t, const int* __restrict__ flagp,
    const float* __restrict__ amax, const float* __restrict__ denarr,
    const void* __restrict__ W1, const void* __restrict__ b1,
    const void* __restrict__ W2, const void* __restrict__ b2,
    float* __restrict__ out0, float* __restrict__ outz, int N)
{
    __shared__ float W1s[34 * HN];
    __shared__ float b1s[HN], W2s[HN];
    __shared__ float b2s;
    const int tid = threadIdx.x;
    const int isbf = flagp[0];
    for (int i = tid; i < 34 * HN; i += 256) W1s[i] = ldf(W1, i, isbf);
    if (tid < HN) {
        b1s[tid] = ldf(b1, tid, isbf);
        W2s[tid] = ldf(W2, tid, isbf);
    }
    if (tid == 0) b2s = ldf(b2, 0, isbf);
    __syncthreads();

    const int lane = tid & 31;
    const int v = blockIdx.x * 8 + (tid >> 5);
    if (v >= N) return;

    float rep = rep_in[(size_t)v * HN + lane];
    float ml  = out0[v];
    float den = denarr[v];
    float zh  = outz[v];
    float am  = amax[0];
    float term = (1e-8f / den) * expf(am - ml);
    float z = zh / (1.0f + term);
    float tv = ldf(t, v, isbf);

    float acc = b1s[lane] + tv * W1s[32 * HN + lane] + z * W1s[33 * HN + lane];
    #pragma unroll
    for (int k = 0; k < HN; ++k)
        acc += __shfl(rep, k, 32) * W1s[k * HN + lane];
    float f1 = fmaxf(acc, 0.f);
    float o = f1 * W2s[lane];
    #pragma unroll
    for (int m = 16; m; m >>= 1) o += __shfl_xor(o, m, 32);

    if (lane == 0) {
        out0[v] = o + b2s;
        outz[v] = z;
    }
}

extern "C" void kernel_launch(void* const* d_in, const int* in_sizes, int n_in,
                              void* d_out, int out_size, void* d_ws, size_t ws_size,
                              hipStream_t stream)
{
    const int N = out_size / 34;   // out[N] + rep[N*32] + z[N]
    const int E = in_sizes[2];

    const void* x    = d_in[0];
    const void* t    = d_in[1];
    const int* row   = (const int*)d_in[2];
    const int* col   = (const int*)d_in[3];
    const void* Wemb = d_in[4];
    const void* bemb = d_in[5];
    const void* Wgcn = d_in[6];
    const void* bgcn = d_in[7];
    const void* W1   = d_in[8];
    const void* b1   = d_in[9];
    const void* W2   = d_in[10];
    const void* b2   = d_in[11];

    const int B   = (N + 255) >> 8;         // coarse buckets (<=512 for N<=131072)
    const int nsb = (N + 2047) / 2048;      // rowptr-scan chunks
    const int NB1 = (E + CH1 - 1) / CH1;    // phase1/bhist blocks

    // ws (~39.2 MB): h | hwbuf(bucketed->hws) | csr_src | rowptr | count(cursor->den)
    //                | bucket_cnt | bucket_base | bucket_cursor | bmax2 | bsum | amax | flag
    char* wsb = (char*)d_ws;
    size_t off = 0;
    float* h        = (float*)(wsb + off); off += (size_t)N * HN * 4;
    size_t hwbytes  = (size_t)N * HN * 4;
    if ((size_t)E * 4 > hwbytes) hwbytes = (size_t)E * 4;
    char*  hwreg    = wsb + off;           off += hwbytes;
    int*   csr_src  = (int*)(wsb + off);   off += (size_t)E * 4;
    int*   rowptr   = (int*)(wsb + off);   off += (size_t)(N + 1) * 4;
    int*   count    = (int*)(wsb + off);   off += (size_t)N * 4;
    int*   bucket_cnt    = (int*)(wsb + off); off += (size_t)B * 4;
    int*   bucket_base   = (int*)(wsb + off); off += (size_t)(B + 1) * 4;
    int*   bucket_cursor = (int*)(wsb + off); off += (size_t)B * 4;
    float* bmax2    = (float*)(wsb + off); off += 256 * 4;
    int*   bsum     = (int*)(wsb + off);   off += (size_t)nsb * 4;
    float* amax     = (float*)(wsb + off); off += 4;
    int*   flag     = (int*)(wsb + off);   off += 4;

    int*   bucketed = (int*)hwreg;         // phase 1..2b
    float* hws      = (float*)hwreg;       // after phase2b

    hipMemsetAsync(bucket_cnt, 0, (size_t)B * 4, stream);

    detect_kernel<<<1, 64, 0, stream>>>((const unsigned int*)x, flag);
    embed1_kernel<<<(N + 31) / 32, 256, 0, stream>>>(x, Wemb, bemb, flag, h, N);

    bhist_kernel<<<NB1, 512, 0, stream>>>(col, bucket_cnt, E, B);
    bscan_kernel<<<1, 512, 0, stream>>>(bucket_cnt, bucket_base,
                                        bucket_cursor, B, E);
    phase1_kernel<<<NB1, 512, 0, stream>>>(row, col, bucket_cursor,
                                           bucketed, E, B);
    phase2a_kernel<<<B, 256, 0, stream>>>(bucketed, bucket_base, count, N);
    scan1_kernel<<<nsb, 256, 0, stream>>>(count, bsum, N);
    scan2_kernel<<<1, 64, 0, stream>>>(bsum, nsb, rowptr, N, E);
    scan3_kernel<<<nsb, 256, 0, stream>>>(count, bsum, rowptr, N);
    phase2b_kernel<<<B, 256, 0, stream>>>(bucketed, bucket_base, rowptr,
                                          count, csr_src, N);
    embed2_kernel<<<(N + 31) / 32, 256, 0, stream>>>(h, Wgcn, rowptr, flag,
                                                     hws, N);

    float* outp = (float*)d_out;
    float* out0 = outp;
    float* outr = outp + N;
    float* outz = outp + (size_t)N * 33;
    float* den  = (float*)count;   // cursor dead after phase2b

    passB_kernel<<<(N + 7) / 8, 256, 0, stream>>>(
        h, hws, csr_src, rowptr, t, bgcn, flag, outr, outz, out0, den, N);
    amax1_kernel<<<256, 256, 0, stream>>>(out0, bmax2, N);
    amax2_kernel<<<1, 256, 0, stream>>>(bmax2, amax);
    final_kernel<<<(N + 7) / 8, 256, 0, stream>>>(
        outr, t, flag, amax, den, W1, b1, W2, b2, out0, outz, N);
}